// Round 2
// baseline (32.839 us; speedup 1.0000x reference)
//
#include <hip/hip_runtime.h>

// RankNetLoss, n=8192.
// Math: sum over ordered pairs i!=j of [0.5*(1-S)*d + log2(1+exp(-d))].
// The 0.5*(1-S)*d part cancels exactly (S symmetric, d antisymmetric).
// Remaining sum folds over unordered pairs:
//   log2(1+e^{-d}) + log2(1+e^{d}) = |d|/ln2 + 2*log2(1 + 2^{-|d|/ln2}).
// So: total = sum_{i<j} [ t + 2*log2(1+exp2(-t)) ],  t = |s_i-s_j|/ln2.
// Output = total / (n*(n-1)).

static constexpr int TILE = 256;

__global__ void rn_zero(float* ws) {
    if (threadIdx.x == 0) ws[0] = 0.0f;
}

__global__ __launch_bounds__(256) void rn_main(const float* __restrict__ s,
                                               float* __restrict__ ws, int n) {
    const int it = blockIdx.y, jt = blockIdx.x;
    if (jt < it) return;  // upper triangle only

    const int t = threadIdx.x;
    const int i = it * TILE + t;
    const int j0 = jt * TILE;

    __shared__ float sj[TILE];
    {
        int j = j0 + t;
        sj[t] = (j < n) ? s[j] : 0.0f;  // guarded; masked out below if OOB
    }
    __syncthreads();

    const float si = (i < n) ? s[i] : 0.0f;
    constexpr float INV_LN2 = 1.44269504088896340736f;

    float acc = 0.0f;

    const bool full_tiles = ((it + 1) * TILE <= n) && ((jt + 1) * TILE <= n);

    if (full_tiles && it != jt) {
        // All pairs in this tile satisfy j > i; no predication needed.
        #pragma unroll 8
        for (int jj = 0; jj < TILE; ++jj) {
            float d = si - sj[jj];
            float a = fabsf(d) * INV_LN2;                  // t = |d|/ln2
            float e = __builtin_amdgcn_exp2f(-a);          // 2^-t
            float l = __builtin_amdgcn_logf(1.0f + e);     // log2(1+2^-t)
            acc += a;
            acc = __builtin_fmaf(2.0f, l, acc);            // acc += t + 2*l
        }
    } else {
        // Diagonal tile and/or edge tile: predicate on j > i (and bounds).
        #pragma unroll 8
        for (int jj = 0; jj < TILE; ++jj) {
            int j = j0 + jj;
            float d = si - sj[jj];
            float a = fabsf(d) * INV_LN2;
            float e = __builtin_amdgcn_exp2f(-a);
            float l = __builtin_amdgcn_logf(1.0f + e);
            float c = __builtin_fmaf(2.0f, l, a);
            bool ok = (j > i) && (j < n) && (i < n);
            acc += ok ? c : 0.0f;
        }
    }

    // Wave-level reduce (64 lanes).
    for (int off = 32; off > 0; off >>= 1)
        acc += __shfl_down(acc, off, 64);

    __shared__ float wpart[4];
    const int lane = t & 63;
    const int w = t >> 6;
    if (lane == 0) wpart[w] = acc;
    __syncthreads();
    if (t == 0) {
        float b = wpart[0] + wpart[1] + wpart[2] + wpart[3];
        atomicAdd(ws, b);
    }
}

__global__ void rn_final(const float* __restrict__ ws, float* __restrict__ out,
                         float inv_pairs) {
    if (threadIdx.x == 0 && blockIdx.x == 0) out[0] = ws[0] * inv_pairs;
}

extern "C" void kernel_launch(void* const* d_in, const int* in_sizes, int n_in,
                              void* d_out, int out_size, void* d_ws, size_t ws_size,
                              hipStream_t stream) {
    const float* s = (const float*)d_in[0];
    // d_in[1] (labels) is mathematically irrelevant: the 0.5*(1-S)*d term
    // cancels over ordered pairs.
    const int n = in_sizes[0];

    float* ws = (float*)d_ws;
    float* out = (float*)d_out;

    rn_zero<<<1, 64, 0, stream>>>(ws);

    const int ntile = (n + TILE - 1) / TILE;
    dim3 grid(ntile, ntile);
    rn_main<<<grid, TILE, 0, stream>>>(s, ws, n);

    const double npairs = (double)n * (double)(n - 1);
    rn_final<<<1, 64, 0, stream>>>(ws, out, (float)(1.0 / npairs));
}

// Round 3
// 21.154 us; speedup vs baseline: 1.5524x; 1.5524x over previous
//
#include <hip/hip_runtime.h>

// RankNetLoss, n=8192.
// sum over ordered pairs i!=j of [0.5*(1-S)*d + log2(1+exp(-d))].
// The 0.5*(1-S)*d term cancels exactly (S symmetric, d antisymmetric) -> labels irrelevant.
// Fold ordered -> unordered pairs:
//   log2(1+e^{-d}) + log2(1+e^{d}) = |d|/ln2 + 2*log2(1 + 2^{-|d|/ln2}).
// total = sum_{i<j} [ a + 2*log2(1+2^{-a}) ],  a = |s_i-s_j|/ln2;  out = total/(n(n-1)).

static constexpr int TI = 256;  // i-extent per block (= block threads)
static constexpr int TJ = 64;   // j-extent per block

__global__ __launch_bounds__(256) void rn_main(const float* __restrict__ s,
                                               float* __restrict__ part, int n) {
    const int it = blockIdx.y, jt = blockIdx.x;
    const int bid = it * gridDim.x + jt;
    const int t = threadIdx.x;

    const int j0 = jt * TJ;
    const int i  = it * TI + t;

    constexpr float INV_LN2 = 1.44269504088896340736f;
    float total = 0.0f;

    // pairs (i<j) exist in this tile iff max j > min i
    if (j0 + TJ - 1 > it * TI) {
        const float si = (i < n) ? s[i] : 0.0f;
        float accA = 0.0f, accL = 0.0f;

        // block-uniform "clean": strictly above diagonal, no edge clipping
        const bool clean = (j0 > it * TI + TI - 1) && (j0 + TJ <= n) && ((it + 1) * TI <= n);
        if (clean) {
            #pragma unroll 16
            for (int jj = 0; jj < TJ; ++jj) {
                float b = s[j0 + jj];                     // block-uniform -> s_load (scalar cache)
                float d = si - b;
                float a = fabsf(d) * INV_LN2;
                float e = __builtin_amdgcn_exp2f(-a);     // 2^-a
                float l = __builtin_amdgcn_logf(1.0f + e);// log2(1+2^-a)
                accA += a;
                accL += l;
            }
        } else {
            #pragma unroll 16
            for (int jj = 0; jj < TJ; ++jj) {
                int j = j0 + jj;
                float b = (j < n) ? s[j] : 0.0f;
                float d = si - b;
                float a = fabsf(d) * INV_LN2;
                float e = __builtin_amdgcn_exp2f(-a);
                float l = __builtin_amdgcn_logf(1.0f + e);
                bool ok = (j > i) && (j < n) && (i < n);
                accA += ok ? a : 0.0f;
                accL += ok ? l : 0.0f;
            }
        }
        total = __builtin_fmaf(2.0f, accL, accA);
    }

    // wave reduce (64 lanes)
    for (int off = 32; off > 0; off >>= 1)
        total += __shfl_down(total, off, 64);

    __shared__ float wpart[TI / 64];
    const int lane = t & 63, w = t >> 6;
    if (lane == 0) wpart[w] = total;
    __syncthreads();
    if (t == 0) {
        float b = 0.0f;
        #pragma unroll
        for (int k = 0; k < TI / 64; ++k) b += wpart[k];
        part[bid] = b;   // every block writes (dense, no atomics, no pre-zero)
    }
}

__global__ __launch_bounds__(1024) void rn_final(const float* __restrict__ part,
                                                 float* __restrict__ out,
                                                 int nblocks, float inv_pairs) {
    const int t = threadIdx.x;
    float a = 0.0f;
    for (int k = t; k < nblocks; k += 1024) a += part[k];
    for (int off = 32; off > 0; off >>= 1)
        a += __shfl_down(a, off, 64);
    __shared__ float wp[16];
    if ((t & 63) == 0) wp[t >> 6] = a;
    __syncthreads();
    if (t == 0) {
        float b = 0.0f;
        #pragma unroll
        for (int k = 0; k < 16; ++k) b += wp[k];
        out[0] = b * inv_pairs;
    }
}

extern "C" void kernel_launch(void* const* d_in, const int* in_sizes, int n_in,
                              void* d_out, int out_size, void* d_ws, size_t ws_size,
                              hipStream_t stream) {
    const float* s = (const float*)d_in[0];
    // d_in[1] (labels) is mathematically irrelevant (antisymmetric term cancels).
    const int n = in_sizes[0];

    float* part = (float*)d_ws;          // gx*gy floats (16 KB at n=8192)
    float* out = (float*)d_out;

    const int gx = (n + TJ - 1) / TJ;    // 128
    const int gy = (n + TI - 1) / TI;    // 32
    dim3 grid(gx, gy);
    rn_main<<<grid, TI, 0, stream>>>(s, part, n);

    const double npairs = (double)n * (double)(n - 1);
    rn_final<<<1, 1024, 0, stream>>>(part, out, gx * gy, (float)(1.0 / npairs));
}

// Round 4
// 18.208 us; speedup vs baseline: 1.8035x; 1.1618x over previous
//
#include <hip/hip_runtime.h>

// RankNetLoss, n=8192.
// sum over ordered pairs i!=j of [0.5*(1-S)*d + log2(1+exp(-d))].
// The 0.5*(1-S)*d term cancels exactly (S symmetric, d antisymmetric) -> labels irrelevant.
// Fold ordered -> unordered pairs:
//   log2(1+e^{-d}) + log2(1+e^{d}) = |d|/ln2 + 2*log2(1 + 2^{-|d|/ln2}).
// total = sum_{i<j} [ a + 2*log2(1+2^{-a}) ],  a = |s_i-s_j|/ln2;  out = total/(n(n-1)).

static constexpr int TI = 256;  // i-extent per block (= block threads)
static constexpr int TJ = 64;   // j-extent per block
static constexpr int R  = TI / TJ;  // 4

__global__ __launch_bounds__(256, 8) void rn_main(const float* __restrict__ s,
                                                  float* __restrict__ part,
                                                  int n, int gx) {
    // Decode linear active-tile id -> (it, jt). Row it has tiles jt in
    // [it*R, gx-1], count = gx - it*R. Uniform (blockIdx-derived) -> scalar loop.
    int rem = blockIdx.x;
    int it = 0;
    while (rem >= gx - it * R) { rem -= gx - it * R; ++it; }
    const int jt = it * R + rem;

    const int t = threadIdx.x;
    const int i = it * TI + t;
    const int j0 = jt * TJ;

    __shared__ float sj[TJ];
    if (t < TJ) {
        int j = j0 + t;
        sj[t] = (j < n) ? s[j] : 0.0f;
    }
    __syncthreads();

    constexpr float INV_LN2 = 1.44269504088896340736f;
    const float si = (i < n) ? s[i] : 0.0f;
    float accA = 0.0f, accL = 0.0f;

    // clean: strictly above the diagonal band and no edge clipping
    const bool clean = (jt >= (it + 1) * R) && (j0 + TJ <= n) && (it * TI + TI <= n);
    if (clean) {
        #pragma unroll 8
        for (int jj = 0; jj < TJ; ++jj) {
            float d = si - sj[jj];                      // ds_read uniform -> broadcast
            float a = fabsf(d) * INV_LN2;
            float e = __builtin_amdgcn_exp2f(-a);       // 2^-a (neg is free src mod)
            float l = __builtin_amdgcn_logf(1.0f + e);  // log2(1+2^-a)
            accA += a;
            accL += l;
        }
    } else {
        #pragma unroll 8
        for (int jj = 0; jj < TJ; ++jj) {
            int j = j0 + jj;
            float d = si - sj[jj];
            float a = fabsf(d) * INV_LN2;
            float e = __builtin_amdgcn_exp2f(-a);
            float l = __builtin_amdgcn_logf(1.0f + e);
            bool ok = (j > i) && (j < n) && (i < n);
            accA += ok ? a : 0.0f;
            accL += ok ? l : 0.0f;
        }
    }
    float total = __builtin_fmaf(2.0f, accL, accA);

    // wave reduce (64 lanes)
    for (int off = 32; off > 0; off >>= 1)
        total += __shfl_down(total, off, 64);

    __shared__ float wpart[TI / 64];
    if ((t & 63) == 0) wpart[t >> 6] = total;
    __syncthreads();
    if (t == 0) {
        float b = 0.0f;
        #pragma unroll
        for (int k = 0; k < TI / 64; ++k) b += wpart[k];
        part[blockIdx.x] = b;   // dense, no atomics, no pre-zero needed
    }
}

__global__ __launch_bounds__(1024) void rn_final(const float* __restrict__ part,
                                                 float* __restrict__ out,
                                                 int nblocks, float inv_pairs) {
    const int t = threadIdx.x;
    float a = 0.0f;
    for (int k = t; k < nblocks; k += 1024) a += part[k];
    for (int off = 32; off > 0; off >>= 1)
        a += __shfl_down(a, off, 64);
    __shared__ float wp[16];
    if ((t & 63) == 0) wp[t >> 6] = a;
    __syncthreads();
    if (t == 0) {
        float b = 0.0f;
        #pragma unroll
        for (int k = 0; k < 16; ++k) b += wp[k];
        out[0] = b * inv_pairs;
    }
}

extern "C" void kernel_launch(void* const* d_in, const int* in_sizes, int n_in,
                              void* d_out, int out_size, void* d_ws, size_t ws_size,
                              hipStream_t stream) {
    const float* s = (const float*)d_in[0];
    // d_in[1] (labels) is mathematically irrelevant (antisymmetric term cancels).
    const int n = in_sizes[0];

    float* part = (float*)d_ws;
    float* out = (float*)d_out;

    const int gx = (n + TJ - 1) / TJ;   // j-tiles (128 at n=8192)
    const int gy = (n + TI - 1) / TI;   // i-tiles (32)

    // number of active tiles: sum over it of max(0, gx - it*R)
    int nactive = 0;
    for (int it = 0; it < gy; ++it) {
        int c = gx - it * R;
        if (c > 0) nactive += c;
    }

    rn_main<<<nactive, TI, 0, stream>>>(s, part, n, gx);

    const double npairs = (double)n * (double)(n - 1);
    rn_final<<<1, 1024, 0, stream>>>(part, out, nactive, (float)(1.0 / npairs));
}

// Round 5
// 15.819 us; speedup vs baseline: 2.0760x; 1.1510x over previous
//
#include <hip/hip_runtime.h>

// RankNetLoss, n=8192.
// sum over ordered pairs i!=j of [0.5*(1-S)*d + log2(1+exp(-d))].
// The 0.5*(1-S)*d term cancels exactly (S symmetric, d antisymmetric) -> labels irrelevant.
// Fold ordered -> unordered pairs:
//   log2(1+e^{-d}) + log2(1+e^{d}) = |d|/ln2 + 2*log2(1 + 2^{-|d|/ln2}).
// Batch the logs: sum_j log2(1+e_j) = log2( prod_j (1+e_j) ).
// Each thread does 64 factors; (1+e) in [1,2] -> prod <= 2^64, fits fp32.
// total = INV_LN2 * sum|d| + 2*log2(prod);  out = total/(n(n-1)).

static constexpr int TI = 256;      // i-extent per block (= block threads)
static constexpr int TJ = 64;       // j-extent per block
static constexpr int R  = TI / TJ;  // 4

__global__ __launch_bounds__(256, 8) void rn_main(const float* __restrict__ s,
                                                  float* __restrict__ part,
                                                  int n, int gx) {
    // Decode linear active-tile id -> (it, jt). Row it has tiles jt in
    // [it*R, gx-1], count = gx - it*R. Uniform -> scalar loop.
    int rem = blockIdx.x;
    int it = 0;
    while (rem >= gx - it * R) { rem -= gx - it * R; ++it; }
    const int jt = it * R + rem;

    const int t = threadIdx.x;
    const int i = it * TI + t;
    const int j0 = jt * TJ;

    __shared__ float sj[TJ];
    if (t < TJ) {
        int j = j0 + t;
        sj[t] = (j < n) ? s[j] : 0.0f;
    }
    __syncthreads();

    constexpr float INV_LN2 = 1.44269504088896340736f;
    const float si = (i < n) ? s[i] : 0.0f;

    float accD = 0.0f;   // sum |d|
    float prod = 1.0f;   // prod (1 + 2^{-|d|/ln2})

    const bool clean = (jt >= (it + 1) * R) && (j0 + TJ <= n) && (it * TI + TI <= n);
    if (clean) {
        #pragma unroll 8
        for (int jj = 0; jj < TJ; ++jj) {
            float d = si - sj[jj];                    // uniform ds_read -> broadcast
            float a = fabsf(d) * INV_LN2;             // abs folds as src modifier
            float e = __builtin_amdgcn_exp2f(-a);     // neg folds as src modifier
            prod = __builtin_fmaf(prod, e, prod);     // prod *= (1+e), single FMA
            accD += fabsf(d);
        }
    } else {
        #pragma unroll 8
        for (int jj = 0; jj < TJ; ++jj) {
            int j = j0 + jj;
            float d = si - sj[jj];
            float a = fabsf(d) * INV_LN2;
            float e = __builtin_amdgcn_exp2f(-a);
            bool ok = (j > i) && (j < n) && (i < n);
            e = ok ? e : 0.0f;                        // masked factor = 1
            prod = __builtin_fmaf(prod, e, prod);
            accD += ok ? fabsf(d) : 0.0f;
        }
    }
    float total = __builtin_fmaf(2.0f, __builtin_amdgcn_logf(prod),
                                 accD * INV_LN2);

    // wave reduce (64 lanes)
    for (int off = 32; off > 0; off >>= 1)
        total += __shfl_down(total, off, 64);

    __shared__ float wpart[TI / 64];
    if ((t & 63) == 0) wpart[t >> 6] = total;
    __syncthreads();
    if (t == 0) {
        float b = 0.0f;
        #pragma unroll
        for (int k = 0; k < TI / 64; ++k) b += wpart[k];
        part[blockIdx.x] = b;   // dense, no atomics, no pre-zero needed
    }
}

__global__ __launch_bounds__(1024) void rn_final(const float* __restrict__ part,
                                                 float* __restrict__ out,
                                                 int nblocks, float inv_pairs) {
    const int t = threadIdx.x;
    float a = 0.0f;
    for (int k = t; k < nblocks; k += 1024) a += part[k];
    for (int off = 32; off > 0; off >>= 1)
        a += __shfl_down(a, off, 64);
    __shared__ float wp[16];
    if ((t & 63) == 0) wp[t >> 6] = a;
    __syncthreads();
    if (t == 0) {
        float b = 0.0f;
        #pragma unroll
        for (int k = 0; k < 16; ++k) b += wp[k];
        out[0] = b * inv_pairs;
    }
}

extern "C" void kernel_launch(void* const* d_in, const int* in_sizes, int n_in,
                              void* d_out, int out_size, void* d_ws, size_t ws_size,
                              hipStream_t stream) {
    const float* s = (const float*)d_in[0];
    // d_in[1] (labels) is mathematically irrelevant (antisymmetric term cancels).
    const int n = in_sizes[0];

    float* part = (float*)d_ws;
    float* out = (float*)d_out;

    const int gx = (n + TJ - 1) / TJ;   // j-tiles (128 at n=8192)
    const int gy = (n + TI - 1) / TI;   // i-tiles (32)

    int nactive = 0;
    for (int it = 0; it < gy; ++it) {
        int c = gx - it * R;
        if (c > 0) nactive += c;
    }

    rn_main<<<nactive, TI, 0, stream>>>(s, part, n, gx);

    const double npairs = (double)n * (double)(n - 1);
    rn_final<<<1, 1024, 0, stream>>>(part, out, nactive, (float)(1.0 / npairs));
}